// Round 11
// baseline (5653.883 us; speedup 1.0000x reference)
//
#include <hip/hip_runtime.h>
#include <stdint.h>

#define NB 64
#define NS 512
#define NI 512
#define NH 512

typedef __attribute__((ext_vector_type(8))) short bf16x8;
typedef __attribute__((ext_vector_type(4))) float f32x4;

__device__ __forceinline__ unsigned short f2bf(float f) {
  unsigned u = __float_as_uint(f);
  return (unsigned short)((u + 0x7fffu + ((u >> 16) & 1u)) >> 16);
}
__device__ __forceinline__ float bf2f(unsigned short h) {
  return __uint_as_float(((unsigned)h) << 16);
}
__device__ __forceinline__ float sigm(float x) { return 1.0f / (1.0f + __expf(-x)); }
__device__ __forceinline__ float tanh_f(float x) {
  float e = __expf(-2.0f * fabsf(x));
  return copysignf((1.0f - e) / (1.0f + e), x);
}

// ws layout (u32 units):
//  [0,512):   flags[8 groups][2 red-waves][32 slices] = steps published (monotonic)
//  [1024,+):  x_bf16 as u16[64][512][512]
#define FLAGS_OFF 0
#define XBF_OFF 1024
#define WS_BYTES_NEEDED ((size_t)XBF_OFF * 4 + (size_t)NB * NS * NI * 2)

__global__ __launch_bounds__(256) void k_xconv(const float* __restrict__ x,
                                               unsigned short* __restrict__ xb) {
  size_t i = ((size_t)blockIdx.x * 256 + threadIdx.x) * 4;
  float4 v = *(const float4*)(x + i);
  ushort4 o;
  o.x = f2bf(v.x); o.y = f2bf(v.y); o.z = f2bf(v.z); o.w = f2bf(v.w);
  *(ushort4*)(xb + i) = o;
}

__global__ __launch_bounds__(256) void k_init(unsigned int* __restrict__ ws) {
  int idx = blockIdx.x * 256 + threadIdx.x;
  if (idx < 512) ws[FLAGS_OFF + idx] = 0u;  // no steps published yet
}

// Persistent cooperative LSTM. grid 256 WGs x 512 thr (R9 shape, decentralized
// consume side, ONE barrier per step).
// Group g = bid&7: 8 batches [g*8,+8). Slice s = bid>>3: h-cols [s*16,+16),
// all 4 gates. Wave w = K-eighth (cols [w*64,+64)).
// Exchange: reducer waves 0,1 publish fp32 h into `out` via sc1 store + vmcnt
// ack + sc1 flag (R9-proven). Each wave then polls ONLY its own 8 producer
// flags (slices 4w..4w+3, both reducer planes) and direct-loads its own h
// fragment from `out` with plain cached loads (per-step-unique addresses ->
// no stale-line hazard; L2-dedup across the group's 32 WGs on one XCD).
// part[] is parity-double-buffered -> no S1; WAR closed transitively by the
// flag graph (wave writes part(t+2,p) only after all group WGs published t+1,
// which requires their reducers read part(t,p) first). Deadlock-free: flags(t+1)
// depend only on own-WG S2(t), never on other WGs' flags(t+1).
__global__ __launch_bounds__(512, 2) void k_lstm(
    const float* __restrict__ Wih, const float* __restrict__ bih,
    const float* __restrict__ Whh, const float* __restrict__ bhh,
    const float* __restrict__ h0, const float* __restrict__ c0,
    float* __restrict__ out, unsigned int* __restrict__ ws) {
  const int tid = threadIdx.x;
  const int lane = tid & 63;
  const int w = tid >> 6;   // K-eighth
  const int q = lane >> 4;
  const int c = lane & 15;
  const int b8 = lane & 7;  // A-frag batch (rows 8-15 duplicate 0-7)
  const int k0 = w * 64;
  const int g = blockIdx.x & 7;
  const int s = blockIdx.x >> 3;

  unsigned int* flagsG = ws + FLAGS_OFF + g * 64;  // [2 red-waves][32 slices]
  const unsigned short* xb = (const unsigned short*)(ws + XBF_OFF);

  // ---- weight fragments (hi/lo bf16 split): 4 gates x 2 K-chunks ----
  bf16x8 wih_hi[4][2], wih_lo[4][2], whh_hi[4][2], whh_lo[4][2];
#pragma unroll
  for (int g4 = 0; g4 < 4; ++g4) {
    const int wrow = g4 * 512 + s * 16 + c;  // B-frag col = c
#pragma unroll
    for (int kc = 0; kc < 2; ++kc) {
      const int kb = k0 + kc * 32 + q * 8;
      const float* pi = Wih + (size_t)wrow * NI + kb;
      const float* ph = Whh + (size_t)wrow * NH + kb;
      float4 i0 = *(const float4*)pi, i1 = *(const float4*)(pi + 4);
      float4 h0v = *(const float4*)ph, h1v = *(const float4*)(ph + 4);
      float vi[8] = {i0.x, i0.y, i0.z, i0.w, i1.x, i1.y, i1.z, i1.w};
      float vh[8] = {h0v.x, h0v.y, h0v.z, h0v.w, h1v.x, h1v.y, h1v.z, h1v.w};
#pragma unroll
      for (int r = 0; r < 8; ++r) {
        unsigned short a = f2bf(vi[r]);
        wih_hi[g4][kc][r] = (short)a;
        wih_lo[g4][kc][r] = (short)f2bf(vi[r] - bf2f(a));
        unsigned short b = f2bf(vh[r]);
        whh_hi[g4][kc][r] = (short)b;
        whh_lo[g4][kc][r] = (short)f2bf(vh[r] - bf2f(b));
      }
    }
  }

  // reducer mapping (waves 0,1): lane -> (batch bgc = g*8 + w*4 + q, col jg)
  const int bgc = g * 8 + ((w * 4 + q) & 7);  // clamped for non-reducer waves
  const int jg = s * 16 + c;
  const float bI = bih[jg] + bhh[jg];
  const float bF = bih[512 + jg] + bhh[512 + jg];
  const float bG = bih[1024 + jg] + bhh[1024 + jg];
  const float bO = bih[1536 + jg] + bhh[1536 + jg];
  float cst = c0[(size_t)bgc * NH + jg];

  // parity-double-buffered partials: [parity][gate][wave][reg][col(+pad)]
  __shared__ float part[2][4][8][4][72];

  // per-wave flag pointer: e=lane&7 -> plane e>>2, slice 4w+(e&3)
  const int e8 = lane & 7;
  const unsigned* fp = flagsG + (e8 >> 2) * 32 + w * 4 + (e8 & 3);

  const unsigned short* xrow = xb + (size_t)(g * 8 + b8) * NS * NI + k0 + q * 8;
  bf16x8 xf0 = *(const bf16x8*)(xrow);
  bf16x8 xf1 = *(const bf16x8*)(xrow + 32);

#pragma unroll 1
  for (int t = 0; t < NS; ++t) {
    // ---- x-path MFMA (h-independent; overlaps other waves' polls) ----
    f32x4 acc[4];
#pragma unroll
    for (int g4 = 0; g4 < 4; ++g4) acc[g4] = (f32x4){0.f, 0.f, 0.f, 0.f};
#pragma unroll
    for (int g4 = 0; g4 < 4; ++g4) {
      acc[g4] = __builtin_amdgcn_mfma_f32_16x16x32_bf16(xf0, wih_hi[g4][0], acc[g4], 0, 0, 0);
      acc[g4] = __builtin_amdgcn_mfma_f32_16x16x32_bf16(xf0, wih_lo[g4][0], acc[g4], 0, 0, 0);
      acc[g4] = __builtin_amdgcn_mfma_f32_16x16x32_bf16(xf1, wih_hi[g4][1], acc[g4], 0, 0, 0);
      acc[g4] = __builtin_amdgcn_mfma_f32_16x16x32_bf16(xf1, wih_lo[g4][1], acc[g4], 0, 0, 0);
    }

    // ---- acquire own h fragment ----
    float4 hA0, hB0, hA1, hB1;
    if (t == 0) {
      const float* hr = h0 + (size_t)(g * 8 + b8) * NH + k0 + q * 8;
      hA0 = *(const float4*)hr;
      hB0 = *(const float4*)(hr + 4);
      hA1 = *(const float4*)(hr + 32);
      hB1 = *(const float4*)(hr + 36);
    } else {
      const unsigned tgt = (unsigned)t;
      unsigned fl = __hip_atomic_load(fp, __ATOMIC_RELAXED, __HIP_MEMORY_SCOPE_AGENT);
      while (!__all((int)(fl >= tgt))) {
        __builtin_amdgcn_s_sleep(1);
        fl = __hip_atomic_load(fp, __ATOMIC_RELAXED, __HIP_MEMORY_SCOPE_AGENT);
      }
      asm volatile("" ::: "memory");  // keep h loads below the poll
      const float* hr = out + ((size_t)(g * 8 + b8) * NS + (t - 1)) * NH + k0 + q * 8;
      hA0 = *(const float4*)hr;
      hB0 = *(const float4*)(hr + 4);
      hA1 = *(const float4*)(hr + 32);
      hB1 = *(const float4*)(hr + 36);
    }

    // ---- h-path: fp32 -> hi/lo bf16 -> 3-term MFMA ----
#pragma unroll
    for (int kc = 0; kc < 2; ++kc) {
      float hv8[8];
      if (kc == 0) {
        hv8[0] = hA0.x; hv8[1] = hA0.y; hv8[2] = hA0.z; hv8[3] = hA0.w;
        hv8[4] = hB0.x; hv8[5] = hB0.y; hv8[6] = hB0.z; hv8[7] = hB0.w;
      } else {
        hv8[0] = hA1.x; hv8[1] = hA1.y; hv8[2] = hA1.z; hv8[3] = hA1.w;
        hv8[4] = hB1.x; hv8[5] = hB1.y; hv8[6] = hB1.z; hv8[7] = hB1.w;
      }
      bf16x8 hh, hl;
#pragma unroll
      for (int r = 0; r < 8; ++r) {
        unsigned short a = f2bf(hv8[r]);
        hh[r] = (short)a;
        hl[r] = (short)f2bf(hv8[r] - bf2f(a));
      }
#pragma unroll
      for (int g4 = 0; g4 < 4; ++g4) {
        acc[g4] = __builtin_amdgcn_mfma_f32_16x16x32_bf16(hh, whh_hi[g4][kc], acc[g4], 0, 0, 0);
        acc[g4] = __builtin_amdgcn_mfma_f32_16x16x32_bf16(hl, whh_hi[g4][kc], acc[g4], 0, 0, 0);
        acc[g4] = __builtin_amdgcn_mfma_f32_16x16x32_bf16(hh, whh_lo[g4][kc], acc[g4], 0, 0, 0);
      }
    }

    const int p = t & 1;
#pragma unroll
    for (int g4 = 0; g4 < 4; ++g4)
#pragma unroll
      for (int r = 0; r < 4; ++r) part[p][g4][w][r][lane] = acc[g4][r];

    asm volatile("s_waitcnt lgkmcnt(0)" ::: "memory");
    __builtin_amdgcn_s_barrier();  // S2: part(p) visible to reducers
    asm volatile("" ::: "memory");

    const int tn = (t + 1 < NS) ? t + 1 : t;
    if (w < 2) {  // reducers: lane owns (b = w*4+q, j = c)
      float sI = bI, sF = bF, sG = bG, sO = bO;
      const int cidx = w * 16 + c;
#pragma unroll
      for (int ww = 0; ww < 8; ++ww) {
        sI += part[p][0][ww][q][cidx];
        sF += part[p][1][ww][q][cidx];
        sG += part[p][2][ww][q][cidx];
        sO += part[p][3][ww][q][cidx];
      }
      float cn = sigm(sF) * cst + sigm(sI) * tanh_f(sG);
      cst = cn;
      float hv = sigm(sO) * tanh_f(cn);

      // publish: sc1 store of hv into out (the output store IS the exchange)
      unsigned* dst = (unsigned*)out + ((size_t)bgc * NS + t) * NH + jg;
      __hip_atomic_store(dst, __float_as_uint(hv), __ATOMIC_RELAXED, __HIP_MEMORY_SCOPE_AGENT);
      asm volatile("s_waitcnt vmcnt(0)" ::: "memory");  // data at coherence point
      if (lane == 0)
        __hip_atomic_store(flagsG + w * 32 + s, (unsigned)(t + 1),
                           __ATOMIC_RELAXED, __HIP_MEMORY_SCOPE_AGENT);

      if (t == NS - 1) {  // final h/c tail (plain; flushed at kernel end)
        size_t hoff = (size_t)NB * NS * NH;
        out[hoff + (size_t)bgc * NH + jg] = hv;
        out[hoff + (size_t)NB * NH + (size_t)bgc * NH + jg] = cn;
      }
    }
    // x prefetch for t+1 (in flight across next poll)
    xf0 = *(const bf16x8*)(xrow + (size_t)tn * NI);
    xf1 = *(const bf16x8*)(xrow + (size_t)tn * NI + 32);
  }
}

extern "C" void kernel_launch(void* const* d_in, const int* in_sizes, int n_in,
                              void* d_out, int out_size, void* d_ws, size_t ws_size,
                              hipStream_t stream) {
  if (ws_size < WS_BYTES_NEEDED) return;  // fail visibly rather than corrupt

  const float* x   = (const float*)d_in[0];
  const float* h0  = (const float*)d_in[1];
  const float* c0  = (const float*)d_in[2];
  const float* Wih = (const float*)d_in[3];
  const float* bih = (const float*)d_in[4];
  const float* Whh = (const float*)d_in[5];
  const float* bhh = (const float*)d_in[6];
  float* out = (float*)d_out;
  unsigned int* ws = (unsigned int*)d_ws;
  unsigned short* xbptr = (unsigned short*)(ws + XBF_OFF);

  k_xconv<<<dim3(16384), dim3(256), 0, stream>>>(x, xbptr);
  k_init<<<dim3(2), dim3(256), 0, stream>>>(ws);

  void* args[] = {(void*)&Wih, (void*)&bih, (void*)&Whh, (void*)&bhh,
                  (void*)&h0,  (void*)&c0,  (void*)&out, (void*)&ws};
  hipLaunchCooperativeKernel((const void*)k_lstm, dim3(256), dim3(512), args, 0, stream);
}

// Round 12
// 1799.449 us; speedup vs baseline: 3.1420x; 3.1420x over previous
//
#include <hip/hip_runtime.h>
#include <stdint.h>

#define NB 64
#define NS 512
#define NI 512
#define NH 512

typedef __attribute__((ext_vector_type(8))) short bf16x8;
typedef __attribute__((ext_vector_type(4))) float f32x4;

__device__ __forceinline__ unsigned short f2bf(float f) {
  unsigned u = __float_as_uint(f);
  return (unsigned short)((u + 0x7fffu + ((u >> 16) & 1u)) >> 16);
}
__device__ __forceinline__ float bf2f(unsigned short h) {
  return __uint_as_float(((unsigned)h) << 16);
}
__device__ __forceinline__ float sigm(float x) { return 1.0f / (1.0f + __expf(-x)); }
__device__ __forceinline__ float tanh_f(float x) {
  float e = __expf(-2.0f * fabsf(x));
  return copysignf((1.0f - e) / (1.0f + e), x);
}

// ws layout (u32 units):
//  [0,512):   flags[8 groups][2 red-waves][32 slices] = steps published (monotonic)
//  [1024,+):  x_bf16 as u16[64][512][512]
#define FLAGS_OFF 0
#define XBF_OFF 1024
#define WS_BYTES_NEEDED ((size_t)XBF_OFF * 4 + (size_t)NB * NS * NI * 2)

__global__ __launch_bounds__(256) void k_xconv(const float* __restrict__ x,
                                               unsigned short* __restrict__ xb) {
  size_t i = ((size_t)blockIdx.x * 256 + threadIdx.x) * 4;
  float4 v = *(const float4*)(x + i);
  ushort4 o;
  o.x = f2bf(v.x); o.y = f2bf(v.y); o.z = f2bf(v.z); o.w = f2bf(v.w);
  *(ushort4*)(xb + i) = o;
}

__global__ __launch_bounds__(256) void k_init(unsigned int* __restrict__ ws) {
  int idx = blockIdx.x * 256 + threadIdx.x;
  if (idx < 512) ws[FLAGS_OFF + idx] = 0u;  // no steps published yet
}

// Persistent cooperative LSTM. grid 256 WGs x 512 thr.
// R9's sync skeleton (sentinel poll + barrier broadcast) + R11's data path
// (direct cached consumer loads, no LDS staging).
// Group g = bid&7: 8 batches [g*8,+8). Slice s = bid>>3: h-cols [s*16,+16),
// all 4 gates. Wave w = K-eighth (cols [w*64,+64)).
// Per step: all waves x-MFMA; sentinel wave 7 polls the group's 64 flags
// (1/lane, sc1 relaxed); raw S1 barrier releases the WG; every wave plain-
// cached-loads its own h fragment from out(t-1) (per-step-unique addresses ->
// no stale-line hazard, proven R9/R11; TCC merges the 32x same-line requests
// per XCD); hi/lo bf16 split -> 12 h-MFMAs -> part -> S2; reducer waves 0,1
// publish fp32 h into `out` via sc1 store + vmcnt ack + sc1 flag (R9-proven).
// WAR on single part buffer: rewritten only after S1(t+1); sentinel passes
// S1(t+1) only after all group flags(t+1), which require this WG's reducers
// to have finished reading part(t). Deadlock-free: flags(t+1) depend only on
// own-WG S2(t).
__global__ __launch_bounds__(512, 2) void k_lstm(
    const float* __restrict__ Wih, const float* __restrict__ bih,
    const float* __restrict__ Whh, const float* __restrict__ bhh,
    const float* __restrict__ h0, const float* __restrict__ c0,
    float* __restrict__ out, unsigned int* __restrict__ ws) {
  const int tid = threadIdx.x;
  const int lane = tid & 63;
  const int w = tid >> 6;   // K-eighth
  const int q = lane >> 4;
  const int c = lane & 15;
  const int b8 = lane & 7;  // A-frag batch (rows 8-15 duplicate 0-7)
  const int k0 = w * 64;
  const int g = blockIdx.x & 7;
  const int s = blockIdx.x >> 3;

  unsigned int* flagsG = ws + FLAGS_OFF + g * 64;  // [2 red-waves][32 slices]
  const unsigned short* xb = (const unsigned short*)(ws + XBF_OFF);

  // ---- weight fragments (hi/lo bf16 split): 4 gates x 2 K-chunks ----
  bf16x8 wih_hi[4][2], wih_lo[4][2], whh_hi[4][2], whh_lo[4][2];
#pragma unroll
  for (int g4 = 0; g4 < 4; ++g4) {
    const int wrow = g4 * 512 + s * 16 + c;  // B-frag col = c
#pragma unroll
    for (int kc = 0; kc < 2; ++kc) {
      const int kb = k0 + kc * 32 + q * 8;
      const float* pi = Wih + (size_t)wrow * NI + kb;
      const float* ph = Whh + (size_t)wrow * NH + kb;
      float4 i0 = *(const float4*)pi, i1 = *(const float4*)(pi + 4);
      float4 h0v = *(const float4*)ph, h1v = *(const float4*)(ph + 4);
      float vi[8] = {i0.x, i0.y, i0.z, i0.w, i1.x, i1.y, i1.z, i1.w};
      float vh[8] = {h0v.x, h0v.y, h0v.z, h0v.w, h1v.x, h1v.y, h1v.z, h1v.w};
#pragma unroll
      for (int r = 0; r < 8; ++r) {
        unsigned short a = f2bf(vi[r]);
        wih_hi[g4][kc][r] = (short)a;
        wih_lo[g4][kc][r] = (short)f2bf(vi[r] - bf2f(a));
        unsigned short b = f2bf(vh[r]);
        whh_hi[g4][kc][r] = (short)b;
        whh_lo[g4][kc][r] = (short)f2bf(vh[r] - bf2f(b));
      }
    }
  }

  // reducer mapping (waves 0,1): lane -> (batch bgc = g*8 + w*4 + q, col jg)
  const int bgc = g * 8 + ((w * 4 + q) & 7);  // clamped for non-reducer waves
  const int jg = s * 16 + c;
  const float bI = bih[jg] + bhh[jg];
  const float bF = bih[512 + jg] + bhh[512 + jg];
  const float bG = bih[1024 + jg] + bhh[1024 + jg];
  const float bO = bih[1536 + jg] + bhh[1536 + jg];
  float cst = c0[(size_t)bgc * NH + jg];

  __shared__ float part[4][8][4][72];  // [gate][wave][reg][col(+pad)]

  const unsigned short* xrow = xb + (size_t)(g * 8 + b8) * NS * NI + k0 + q * 8;
  bf16x8 xf0 = *(const bf16x8*)(xrow);
  bf16x8 xf1 = *(const bf16x8*)(xrow + 32);

#pragma unroll 1
  for (int t = 0; t < NS; ++t) {
    // ---- x-path MFMA (h-independent; producers may still be publishing) ----
    f32x4 acc[4];
#pragma unroll
    for (int g4 = 0; g4 < 4; ++g4) acc[g4] = (f32x4){0.f, 0.f, 0.f, 0.f};
#pragma unroll
    for (int g4 = 0; g4 < 4; ++g4) {
      acc[g4] = __builtin_amdgcn_mfma_f32_16x16x32_bf16(xf0, wih_hi[g4][0], acc[g4], 0, 0, 0);
      acc[g4] = __builtin_amdgcn_mfma_f32_16x16x32_bf16(xf0, wih_lo[g4][0], acc[g4], 0, 0, 0);
      acc[g4] = __builtin_amdgcn_mfma_f32_16x16x32_bf16(xf1, wih_hi[g4][1], acc[g4], 0, 0, 0);
      acc[g4] = __builtin_amdgcn_mfma_f32_16x16x32_bf16(xf1, wih_lo[g4][1], acc[g4], 0, 0, 0);
    }

    // ---- sentinel wave 7: poll all 64 group flags (1 per lane) ----
    if (w == 7 && t > 0) {
      const unsigned tgt = (unsigned)t;
      const unsigned* fp = flagsG + lane;
      unsigned fl = __hip_atomic_load(fp, __ATOMIC_RELAXED, __HIP_MEMORY_SCOPE_AGENT);
      while (!__all((int)(fl >= tgt)))
        fl = __hip_atomic_load(fp, __ATOMIC_RELAXED, __HIP_MEMORY_SCOPE_AGENT);
    }
    asm volatile("" ::: "memory");
    __builtin_amdgcn_s_barrier();  // S1: h(t-1) fully published
    asm volatile("" ::: "memory");

    // ---- all waves: direct cached load of own h fragment ----
    float4 hA0, hB0, hA1, hB1;
    {
      const float* hr = (t == 0)
          ? (h0 + (size_t)(g * 8 + b8) * NH + k0 + q * 8)
          : (out + ((size_t)(g * 8 + b8) * NS + (t - 1)) * NH + k0 + q * 8);
      hA0 = *(const float4*)hr;
      hB0 = *(const float4*)(hr + 4);
      hA1 = *(const float4*)(hr + 32);
      hB1 = *(const float4*)(hr + 36);
    }

    // ---- h-path: fp32 -> hi/lo bf16 -> 3-term MFMA ----
#pragma unroll
    for (int kc = 0; kc < 2; ++kc) {
      float hv8[8];
      if (kc == 0) {
        hv8[0] = hA0.x; hv8[1] = hA0.y; hv8[2] = hA0.z; hv8[3] = hA0.w;
        hv8[4] = hB0.x; hv8[5] = hB0.y; hv8[6] = hB0.z; hv8[7] = hB0.w;
      } else {
        hv8[0] = hA1.x; hv8[1] = hA1.y; hv8[2] = hA1.z; hv8[3] = hA1.w;
        hv8[4] = hB1.x; hv8[5] = hB1.y; hv8[6] = hB1.z; hv8[7] = hB1.w;
      }
      bf16x8 hh, hl;
#pragma unroll
      for (int r = 0; r < 8; ++r) {
        unsigned short a = f2bf(hv8[r]);
        hh[r] = (short)a;
        hl[r] = (short)f2bf(hv8[r] - bf2f(a));
      }
#pragma unroll
      for (int g4 = 0; g4 < 4; ++g4) {
        acc[g4] = __builtin_amdgcn_mfma_f32_16x16x32_bf16(hh, whh_hi[g4][kc], acc[g4], 0, 0, 0);
        acc[g4] = __builtin_amdgcn_mfma_f32_16x16x32_bf16(hl, whh_hi[g4][kc], acc[g4], 0, 0, 0);
        acc[g4] = __builtin_amdgcn_mfma_f32_16x16x32_bf16(hh, whh_lo[g4][kc], acc[g4], 0, 0, 0);
      }
    }

#pragma unroll
    for (int g4 = 0; g4 < 4; ++g4)
#pragma unroll
      for (int r = 0; r < 4; ++r) part[g4][w][r][lane] = acc[g4][r];

    asm volatile("s_waitcnt lgkmcnt(0)" ::: "memory");
    __builtin_amdgcn_s_barrier();  // S2: part visible to reducers
    asm volatile("" ::: "memory");

    const int tn = (t + 1 < NS) ? t + 1 : t;
    if (w < 2) {  // reducers: lane owns (b = w*4+q, j = c)
      float sI = bI, sF = bF, sG = bG, sO = bO;
      const int cidx = w * 16 + c;
#pragma unroll
      for (int ww = 0; ww < 8; ++ww) {
        sI += part[0][ww][q][cidx];
        sF += part[1][ww][q][cidx];
        sG += part[2][ww][q][cidx];
        sO += part[3][ww][q][cidx];
      }
      float cn = sigm(sF) * cst + sigm(sI) * tanh_f(sG);
      cst = cn;
      float hv = sigm(sO) * tanh_f(cn);

      // publish: sc1 store of hv into out (the output store IS the exchange)
      unsigned* dst = (unsigned*)out + ((size_t)bgc * NS + t) * NH + jg;
      __hip_atomic_store(dst, __float_as_uint(hv), __ATOMIC_RELAXED, __HIP_MEMORY_SCOPE_AGENT);
      asm volatile("s_waitcnt vmcnt(0)" ::: "memory");  // data at coherence point
      if (lane == 0)
        __hip_atomic_store(flagsG + w * 32 + s, (unsigned)(t + 1),
                           __ATOMIC_RELAXED, __HIP_MEMORY_SCOPE_AGENT);

      if (t == NS - 1) {  // final h/c tail (plain; flushed at kernel end)
        size_t hoff = (size_t)NB * NS * NH;
        out[hoff + (size_t)bgc * NH + jg] = hv;
        out[hoff + (size_t)NB * NH + (size_t)bgc * NH + jg] = cn;
      }
    }
    // x prefetch for t+1 (in flight across next step's S1)
    xf0 = *(const bf16x8*)(xrow + (size_t)tn * NI);
    xf1 = *(const bf16x8*)(xrow + (size_t)tn * NI + 32);
  }
}

extern "C" void kernel_launch(void* const* d_in, const int* in_sizes, int n_in,
                              void* d_out, int out_size, void* d_ws, size_t ws_size,
                              hipStream_t stream) {
  if (ws_size < WS_BYTES_NEEDED) return;  // fail visibly rather than corrupt

  const float* x   = (const float*)d_in[0];
  const float* h0  = (const float*)d_in[1];
  const float* c0  = (const float*)d_in[2];
  const float* Wih = (const float*)d_in[3];
  const float* bih = (const float*)d_in[4];
  const float* Whh = (const float*)d_in[5];
  const float* bhh = (const float*)d_in[6];
  float* out = (float*)d_out;
  unsigned int* ws = (unsigned int*)d_ws;
  unsigned short* xbptr = (unsigned short*)(ws + XBF_OFF);

  k_xconv<<<dim3(16384), dim3(256), 0, stream>>>(x, xbptr);
  k_init<<<dim3(2), dim3(256), 0, stream>>>(ws);

  void* args[] = {(void*)&Wih, (void*)&bih, (void*)&Whh, (void*)&bhh,
                  (void*)&h0,  (void*)&c0,  (void*)&out, (void*)&ws};
  hipLaunchCooperativeKernel((const void*)k_lstm, dim3(256), dim3(512), args, 0, stream);
}